// Round 1
// baseline (281.262 us; speedup 1.0000x reference)
//
#include <hip/hip_runtime.h>
#include <hip/hip_bf16.h>

typedef __attribute__((ext_vector_type(8))) __bf16 bf16x8;
typedef __attribute__((ext_vector_type(4))) float f32x4;

#define S_TOK 4096
#define NB 2
#define NH 16
#define DH 128
#define DEG 4
#define SSP 1024
#define QB 64
#define KB 64
#define NQT (SSP / QB)
#define TOKS (NB * NH * DH) /* 4096 floats per token */
#define SCALE 0.08838834764831845f

union U8 {
  bf16x8 v;
  unsigned u[4];
  unsigned short s[8];
};

__device__ __forceinline__ unsigned short f2bf(float x) {
  unsigned u = __builtin_bit_cast(unsigned, x);
  u = (u + 0x7fffu + ((u >> 16) & 1u)) >> 16;  // RNE, no NaN in data
  return (unsigned short)u;
}

// LDS: K tile [64][128] bf16, row-major, XOR-swizzled (byte ^= (row&7)<<4) -> 16384 B
//      V^T tile: 128 rows (d) x 64 cols (s) bf16, row pitch 132 B          -> 16896 B
__global__ __launch_bounds__(256, 2) void mlsa_fused(
    const float* __restrict__ Qg, const float* __restrict__ Kg,
    const float* __restrict__ Vg, float* __restrict__ Og,
    float* __restrict__ Dg) {
  __shared__ __align__(16) char lds[KB * 256 + DH * 132];
  char* KL = lds;
  char* VT = lds + KB * 256;

  const int bid = blockIdx.x;
  const int jperm = bid >> 5;  // 0..15
  // interleave heavy (high qt) and light q-tiles for load balance
  const int qt = (jperm & 1) ? (jperm >> 1) : (NQT - 1 - (jperm >> 1));
  const int bh = bid & 31;
  const int b = bh >> 4;
  const int h = bh & 15;
  const int hm4 = h & 3;
  const int tid = (int)threadIdx.x;
  const int wv = tid >> 6;
  const int ln = tid & 63;
  const int g = ln >> 4;   // 16-lane group
  const int c = ln & 15;   // lane-in-group
  const size_t bhoff = (size_t)b * (NH * DH) + (size_t)h * DH;

  // ---- zero-fill the 3 non-selected token offsets for this (qt,b,h) ----
  {
    const f32x4 z = {0.f, 0.f, 0.f, 0.f};
    for (int u = 0; u < 24; ++u) {
      int fid = u * 256 + tid;       // 0..6143 float4 ids
      int row = fid >> 5;            // 0..191 (3 offsets x 64 q-rows)
      int col = fid & 31;
      int rr = row >> 6;             // 0..2
      int qi = qt * QB + (row & 63);
      int off = (hm4 + 1 + rr) & 3;  // the 3 offsets != hm4
      *(f32x4*)(Og + (size_t)(qi * DEG + off) * TOKS + bhoff + col * 4) = z;
    }
  }

  const int qbase = qt * QB + wv * 16;
  const int q_sp = qbase + c;  // this lane's sparse q index (scores column)

  // ---- hoist Q fragments (pre-scaled), B-operand layout ----
  bf16x8 qf[4];
  {
    const float* qrow = Qg + (size_t)(q_sp * DEG + hm4) * TOKS + bhoff;
    #pragma unroll
    for (int dc = 0; dc < 4; ++dc) {
      int d0 = dc * 32 + g * 8;
      f32x4 x0 = *(const f32x4*)(qrow + d0);
      f32x4 x1 = *(const f32x4*)(qrow + d0 + 4);
      U8 t;
      #pragma unroll
      for (int i = 0; i < 4; ++i) {
        t.s[i] = f2bf(x0[i] * SCALE);
        t.s[4 + i] = f2bf(x1[i] * SCALE);
      }
      qf[dc] = t.v;
    }
  }

  float m_run = -1e30f, l_run = 0.f;
  f32x4 acc[8];
  #pragma unroll
  for (int i = 0; i < 8; ++i) acc[i] = (f32x4){0.f, 0.f, 0.f, 0.f};

  const int krow = tid >> 2;        // 0..63 K-stage row
  const int kd0 = (tid & 3) * 8;    // coalesced 128B per 4 lanes
  const int vd4 = tid & 31;         // V-stage d/4
  const int vsp = tid >> 5;         // 0..7

  for (int kt = 0; kt <= qt; ++kt) {
    __syncthreads();  // protect LDS from previous iter's readers
    // ---- stage K tile (bf16, swizzled row-major) ----
    {
      const float* kr = Kg + (size_t)((kt * KB + krow) * DEG + hm4) * TOKS + bhoff;
      #pragma unroll
      for (int p4 = 0; p4 < 4; ++p4) {
        int d = kd0 + p4 * 32;
        f32x4 x0 = *(const f32x4*)(kr + d);
        f32x4 x1 = *(const f32x4*)(kr + d + 4);
        U8 t;
        #pragma unroll
        for (int i = 0; i < 4; ++i) {
          t.s[i] = f2bf(x0[i]);
          t.s[4 + i] = f2bf(x1[i]);
        }
        int byte = (krow * 256 + d * 2) ^ ((krow & 7) << 4);
        *(bf16x8*)(KL + byte) = t.v;
      }
    }
    // ---- stage V^T tile (bf16 pairs packed along s) ----
    {
      #pragma unroll
      for (int pp = 0; pp < 4; ++pp) {
        int s = pp * 16 + vsp * 2;
        const float* vr0 = Vg + (size_t)((kt * KB + s) * DEG + hm4) * TOKS + bhoff + vd4 * 4;
        const float* vr1 = vr0 + (size_t)DEG * TOKS;  // s+1 -> token+4
        f32x4 x0 = *(const f32x4*)vr0;
        f32x4 x1 = *(const f32x4*)vr1;
        #pragma unroll
        for (int j = 0; j < 4; ++j) {
          unsigned w = (unsigned)f2bf(x0[j]) | ((unsigned)f2bf(x1[j]) << 16);
          *(unsigned*)(VT + (vd4 * 4 + j) * 132 + s * 2) = w;
        }
      }
    }
    __syncthreads();

    // ---- QK^T swapped: D[k_local][q] = K . Q ----
    f32x4 sc[4];
    #pragma unroll
    for (int cb = 0; cb < 4; ++cb) sc[cb] = (f32x4){0.f, 0.f, 0.f, 0.f};
    #pragma unroll
    for (int cb = 0; cb < 4; ++cb) {
      int rbase = (cb * 16 + c) * 256;
      int sw = (c & 7) << 4;  // (row&7) == (c&7) since cb*16 % 8 == 0
      #pragma unroll
      for (int dc = 0; dc < 4; ++dc) {
        int byte = (rbase + (dc * 32 + g * 8) * 2) ^ sw;
        bf16x8 kf = *(const bf16x8*)(KL + byte);
        sc[cb] = __builtin_amdgcn_mfma_f32_16x16x32_bf16(kf, qf[dc], sc[cb], 0, 0, 0);
      }
    }

    // ---- causal mask + online softmax (lane owns one q-column) ----
    float p[4][4];
    float mt = -1e30f;
    #pragma unroll
    for (int cb = 0; cb < 4; ++cb) {
      #pragma unroll
      for (int r = 0; r < 4; ++r) {
        int ksp = kt * KB + cb * 16 + g * 4 + r;  // C row = k_local
        float v = (ksp <= q_sp) ? sc[cb][r] : -1e30f;
        p[cb][r] = v;
        mt = fmaxf(mt, v);
      }
    }
    mt = fmaxf(mt, __shfl_xor(mt, 16));
    mt = fmaxf(mt, __shfl_xor(mt, 32));
    float m_new = fmaxf(m_run, mt);
    float resc = __expf(m_run - m_new);
    m_run = m_new;
    float ls = 0.f;
    #pragma unroll
    for (int cb = 0; cb < 4; ++cb) {
      #pragma unroll
      for (int r = 0; r < 4; ++r) {
        float e = __expf(p[cb][r] - m_new);
        p[cb][r] = e;
        ls += e;
      }
    }
    ls += __shfl_xor(ls, 16);
    ls += __shfl_xor(ls, 32);
    l_run = l_run * resc + ls;
    #pragma unroll
    for (int r = 0; r < 4; ++r) {
      float f = __shfl(resc, g * 4 + r);  // factor for acc row q_local=4g+r
      #pragma unroll
      for (int db = 0; db < 8; ++db) acc[db][r] *= f;
    }

    // ---- redistribute P into A-operand fragments ----
    unsigned pk2[4][2];
    #pragma unroll
    for (int cb = 0; cb < 4; ++cb) {
      #pragma unroll
      for (int rp = 0; rp < 2; ++rp)
        pk2[cb][rp] = (unsigned)f2bf(p[cb][2 * rp]) |
                      ((unsigned)f2bf(p[cb][2 * rp + 1]) << 16);
    }
    // dest lane (g,c) needs s = sb*32+8g+e: src group (2g)&3 (e<4) / (2g+1)&3 (e>=4),
    // cb = 2sb + (g>>1), r = e&3
    const int srcA = c + 16 * ((2 * g) & 3);
    const int srcB = c + 16 * ((2 * g + 1) & 3);
    const bool hi = (g & 2) != 0;
    #pragma unroll
    for (int sb = 0; sb < 2; ++sb) {
      unsigned a0 = (unsigned)__shfl((int)pk2[2 * sb][0], srcA);
      unsigned b0 = (unsigned)__shfl((int)pk2[2 * sb + 1][0], srcA);
      unsigned a1 = (unsigned)__shfl((int)pk2[2 * sb][1], srcA);
      unsigned b1 = (unsigned)__shfl((int)pk2[2 * sb + 1][1], srcA);
      unsigned a2 = (unsigned)__shfl((int)pk2[2 * sb][0], srcB);
      unsigned b2 = (unsigned)__shfl((int)pk2[2 * sb + 1][0], srcB);
      unsigned a3 = (unsigned)__shfl((int)pk2[2 * sb][1], srcB);
      unsigned b3 = (unsigned)__shfl((int)pk2[2 * sb + 1][1], srcB);
      U8 pa;
      pa.u[0] = hi ? b0 : a0;
      pa.u[1] = hi ? b1 : a1;
      pa.u[2] = hi ? b2 : a2;
      pa.u[3] = hi ? b3 : a3;
      // ---- PV: acc[db] += P[16q x 32s] * V[32s x 16d] ----
      #pragma unroll
      for (int db = 0; db < 8; ++db) {
        int byte = (db * 16 + c) * 132 + (sb * 32 + g * 8) * 2;
        U8 vb;
        vb.u[0] = *(const unsigned*)(VT + byte);
        vb.u[1] = *(const unsigned*)(VT + byte + 4);
        vb.u[2] = *(const unsigned*)(VT + byte + 8);
        vb.u[3] = *(const unsigned*)(VT + byte + 12);
        acc[db] = __builtin_amdgcn_mfma_f32_16x16x32_bf16(pa.v, vb.v, acc[db], 0, 0, 0);
      }
    }
  }

  // ---- epilogue: normalize, scatter ctx, write denom ----
  float inv = 1.0f / l_run;
  #pragma unroll
  for (int r = 0; r < 4; ++r) {
    float fi = __shfl(inv, g * 4 + r);
    int q2 = qbase + g * 4 + r;
    float* orow = Og + (size_t)(q2 * DEG + hm4) * TOKS + bhoff;
    #pragma unroll
    for (int db = 0; db < 8; ++db) orow[db * 16 + c] = acc[db][r] * fi;
  }
  if (g == 0) Dg[(size_t)(qbase + c) * (NB * NH) + b * NH + h] = l_run;
}

extern "C" void kernel_launch(void* const* d_in, const int* in_sizes, int n_in,
                              void* d_out, int out_size, void* d_ws, size_t ws_size,
                              hipStream_t stream) {
  (void)in_sizes; (void)n_in; (void)out_size; (void)d_ws; (void)ws_size;
  const float* q = (const float*)d_in[0];
  const float* k = (const float*)d_in[1];
  const float* v = (const float*)d_in[2];
  float* out = (float*)d_out;
  float* den = out + (size_t)S_TOK * NB * NH * DH;
  mlsa_fused<<<dim3(NQT * NB * NH), dim3(256), 0, stream>>>(q, k, v, out, den);
}

// Round 2
// 208.425 us; speedup vs baseline: 1.3495x; 1.3495x over previous
//
#include <hip/hip_runtime.h>
#include <hip/hip_bf16.h>

typedef __attribute__((ext_vector_type(8))) __bf16 bf16x8;
typedef __attribute__((ext_vector_type(4))) float f32x4;

#define S_TOK 4096
#define NB 2
#define NH 16
#define DH 128
#define DEG 4
#define SSP 1024
#define QB 64
#define KB 64
#define NQT (SSP / QB)
#define TOKS (NB * NH * DH) /* 4096 floats per token */
#define SCALE 0.08838834764831845f
#define VP 132

union U8 {
  bf16x8 v;
  unsigned u[4];
  unsigned short s[8];
};

__device__ __forceinline__ unsigned short f2bfu(float x) {
  __bf16 b = (__bf16)x;  // RNE; compiler can pair into v_cvt_pk_bf16_f32
  return __builtin_bit_cast(unsigned short, b);
}
__device__ __forceinline__ unsigned pkbf(float lo, float hi) {
  return (unsigned)f2bfu(lo) | ((unsigned)f2bfu(hi) << 16);
}

// LDS: K tile [64][128] bf16 row-major, XOR swizzle byte^=(row&7)<<4  -> 16384 B
//      V^T tile: 128 d-rows x 64 s-cols bf16, row pitch 132 B         -> 16896 B
__global__ __launch_bounds__(256, 2) void mlsa_fused(
    const float* __restrict__ Qg, const float* __restrict__ Kg,
    const float* __restrict__ Vg, float* __restrict__ Og,
    float* __restrict__ Dg) {
  __shared__ __align__(16) char lds[KB * 256 + DH * VP];
  char* KL = lds;
  char* VT = lds + KB * 256;

  const int bid = blockIdx.x;
  const int jperm = bid >> 5;
  // balance: blocks bid and bid+256 land on the same CU (round-robin);
  // f(j)=j (j<8), f(j)=23-j (j>=8) makes every pair sum to 17 tile-steps
  const int qt = (jperm < 8) ? jperm : 23 - jperm;
  const int bh = bid & 31;
  const int b = bh >> 4;
  const int h = bh & 15;
  const int hm4 = h & 3;
  const int tid = (int)threadIdx.x;
  const int wv = tid >> 6;
  const int ln = tid & 63;
  const int g = ln >> 4;
  const int c = ln & 15;
  const size_t bhoff = (size_t)b * (NH * DH) + (size_t)h * DH;

  const int qbase = qt * QB + wv * 16;
  const int q_sp = qbase + c;

  const int krow = tid >> 2;      // K-stage row 0..63
  const int kd0 = (tid & 3) * 8;  // 4 lanes cover one 128-float row
  const int vd4 = tid & 31;       // V-stage d/4
  const int vsp = tid >> 5;       // 0..7

  // ---- issue Q loads first (oldest in vmcnt FIFO) ----
  f32x4 qraw[8];
  {
    const float* qrow = Qg + (size_t)(q_sp * DEG + hm4) * TOKS + bhoff + g * 8;
    #pragma unroll
    for (int dc = 0; dc < 4; ++dc) {
      qraw[2 * dc] = *(const f32x4*)(qrow + dc * 32);
      qraw[2 * dc + 1] = *(const f32x4*)(qrow + dc * 32 + 4);
    }
  }
  // ---- issue tile-0 K/V loads ----
  f32x4 kreg[8], vreg[8];
  {
    const float* kr = Kg + (size_t)(krow * DEG + hm4) * TOKS + bhoff + kd0;
    #pragma unroll
    for (int p4 = 0; p4 < 4; ++p4) {
      kreg[2 * p4] = *(const f32x4*)(kr + p4 * 32);
      kreg[2 * p4 + 1] = *(const f32x4*)(kr + p4 * 32 + 4);
    }
    #pragma unroll
    for (int pp = 0; pp < 4; ++pp) {
      int s = pp * 16 + vsp * 2;
      const float* vr = Vg + (size_t)(s * DEG + hm4) * TOKS + bhoff + vd4 * 4;
      vreg[2 * pp] = *(const f32x4*)vr;
      vreg[2 * pp + 1] = *(const f32x4*)(vr + (size_t)DEG * TOKS);
    }
  }

  // ---- zero-fill the 3 non-selected token offsets (overlaps loads) ----
  {
    const f32x4 z = {0.f, 0.f, 0.f, 0.f};
    for (int u = 0; u < 24; ++u) {
      int fid = u * 256 + tid;
      int row = fid >> 5;
      int col = fid & 31;
      int rr = row >> 6;
      int qi = qt * QB + (row & 63);
      int off = (hm4 + 1 + rr) & 3;
      *(f32x4*)(Og + (size_t)(qi * DEG + off) * TOKS + bhoff + col * 4) = z;
    }
  }

  // ---- convert Q (pre-scaled), B-operand layout ----
  bf16x8 qf[4];
  #pragma unroll
  for (int dc = 0; dc < 4; ++dc) {
    U8 t;
    #pragma unroll
    for (int i = 0; i < 4; ++i) {
      t.s[i] = f2bfu(qraw[2 * dc][i] * SCALE);
      t.s[4 + i] = f2bfu(qraw[2 * dc + 1][i] * SCALE);
    }
    qf[dc] = t.v;
  }

  // staging: convert (overlapped with compute) then write (between barriers)
  U8 kpk[4];
  unsigned vpk[4][4];
  auto conv = [&]() {
    #pragma unroll
    for (int p4 = 0; p4 < 4; ++p4) {
      #pragma unroll
      for (int i = 0; i < 4; ++i) {
        kpk[p4].s[i] = f2bfu(kreg[2 * p4][i]);
        kpk[p4].s[4 + i] = f2bfu(kreg[2 * p4 + 1][i]);
      }
    }
    #pragma unroll
    for (int pp = 0; pp < 4; ++pp) {
      #pragma unroll
      for (int j = 0; j < 4; ++j)
        vpk[pp][j] = pkbf(vreg[2 * pp][j], vreg[2 * pp + 1][j]);
    }
  };
  auto wr = [&]() {
    #pragma unroll
    for (int p4 = 0; p4 < 4; ++p4) {
      int d = kd0 + p4 * 32;
      int byte = (krow * 256 + d * 2) ^ ((krow & 7) << 4);
      *(bf16x8*)(KL + byte) = kpk[p4].v;
    }
    #pragma unroll
    for (int pp = 0; pp < 4; ++pp) {
      int s = pp * 16 + vsp * 2;
      #pragma unroll
      for (int j = 0; j < 4; ++j)
        *(unsigned*)(VT + (vd4 * 4 + j) * VP + s * 2) = vpk[pp][j];
    }
  };

  conv();
  wr();
  __syncthreads();

  float m_run = -1e30f, m_true = -1e30f, l_run = 0.f;
  f32x4 acc[8];
  #pragma unroll
  for (int i = 0; i < 8; ++i) acc[i] = (f32x4){0.f, 0.f, 0.f, 0.f};

  for (int kt = 0; kt <= qt; ++kt) {
    const bool pf = (kt < qt);
    // ---- T14: issue next tile's loads; they fly under this tile's compute ----
    if (pf) {
      const float* kr =
          Kg + (size_t)(((kt + 1) * KB + krow) * DEG + hm4) * TOKS + bhoff + kd0;
      #pragma unroll
      for (int p4 = 0; p4 < 4; ++p4) {
        kreg[2 * p4] = *(const f32x4*)(kr + p4 * 32);
        kreg[2 * p4 + 1] = *(const f32x4*)(kr + p4 * 32 + 4);
      }
      #pragma unroll
      for (int pp = 0; pp < 4; ++pp) {
        int s = (kt + 1) * KB + pp * 16 + vsp * 2;
        const float* vr = Vg + (size_t)(s * DEG + hm4) * TOKS + bhoff + vd4 * 4;
        vreg[2 * pp] = *(const f32x4*)vr;
        vreg[2 * pp + 1] = *(const f32x4*)(vr + (size_t)DEG * TOKS);
      }
      __builtin_amdgcn_sched_barrier(0);  // pin load issue before compute
    }

    // ---- QK^T swapped: C[k_local][q] = K . Q ----
    const int cbmax = pf ? 3 : wv;  // last tile: cb>wv fully masked
    f32x4 sc[4];
    #pragma unroll
    for (int cb = 0; cb < 4; ++cb) sc[cb] = (f32x4){0.f, 0.f, 0.f, 0.f};
    #pragma unroll
    for (int cb = 0; cb < 4; ++cb) {
      if (cb <= cbmax) {
        int rbase = (cb * 16 + c) * 256;
        int sw = (c & 7) << 4;
        #pragma unroll
        for (int dc = 0; dc < 4; ++dc) {
          int byte = (rbase + (dc * 32 + g * 8) * 2) ^ sw;
          bf16x8 kf = *(const bf16x8*)(KL + byte);
          sc[cb] = __builtin_amdgcn_mfma_f32_16x16x32_bf16(kf, qf[dc], sc[cb], 0, 0, 0);
        }
      }
    }

    // ---- mask + online softmax (lane owns q-column c) ----
    float p[4][4];
    float mt = -1e30f;
    if (pf) {
      #pragma unroll
      for (int cb = 0; cb < 4; ++cb) {
        #pragma unroll
        for (int r = 0; r < 4; ++r) {
          float v = sc[cb][r];
          p[cb][r] = v;
          mt = fmaxf(mt, v);
        }
      }
    } else {
      const int qloc = wv * 16 + c;
      #pragma unroll
      for (int cb = 0; cb < 4; ++cb) {
        #pragma unroll
        for (int r = 0; r < 4; ++r) {
          int kloc = cb * 16 + g * 4 + r;
          float v = (cb <= cbmax && kloc <= qloc) ? sc[cb][r] : -1e30f;
          p[cb][r] = v;
          mt = fmaxf(mt, v);
        }
      }
    }
    mt = fmaxf(mt, __shfl_xor(mt, 16));
    mt = fmaxf(mt, __shfl_xor(mt, 32));
    m_true = fmaxf(m_true, mt);

    float resc = 1.0f;
    if (!__all(mt <= m_run + 8.0f)) {  // T13 defer-max
      float m_new = fmaxf(m_run, mt);
      resc = __expf(m_run - m_new);
      m_run = m_new;
      #pragma unroll
      for (int r = 0; r < 4; ++r) {
        float f = __shfl(resc, g * 4 + r);
        #pragma unroll
        for (int db = 0; db < 8; ++db) acc[db][r] *= f;
      }
    }
    float ls = 0.f;
    #pragma unroll
    for (int cb = 0; cb < 4; ++cb) {
      #pragma unroll
      for (int r = 0; r < 4; ++r) {
        float e = __expf(p[cb][r] - m_run);
        p[cb][r] = e;
        ls += e;
      }
    }
    ls += __shfl_xor(ls, 16);
    ls += __shfl_xor(ls, 32);
    l_run = l_run * resc + ls;

    // ---- redistribute P into A-operand fragments ----
    unsigned pk2[4][2];
    #pragma unroll
    for (int cb = 0; cb < 4; ++cb) {
      pk2[cb][0] = pkbf(p[cb][0], p[cb][1]);
      pk2[cb][1] = pkbf(p[cb][2], p[cb][3]);
    }
    const int srcA = c + 16 * ((2 * g) & 3);
    const int srcB = c + 16 * ((2 * g + 1) & 3);
    const bool hi = (g & 2) != 0;
    const int sbmax = pf ? 1 : (wv >> 1);  // last tile: sb=1 dead for wv<2
    #pragma unroll
    for (int sb = 0; sb < 2; ++sb) {
      if (sb <= sbmax) {
        unsigned a0 = (unsigned)__shfl((int)pk2[2 * sb][0], srcA);
        unsigned b0 = (unsigned)__shfl((int)pk2[2 * sb + 1][0], srcA);
        unsigned a1 = (unsigned)__shfl((int)pk2[2 * sb][1], srcA);
        unsigned b1 = (unsigned)__shfl((int)pk2[2 * sb + 1][1], srcA);
        unsigned a2 = (unsigned)__shfl((int)pk2[2 * sb][0], srcB);
        unsigned b2 = (unsigned)__shfl((int)pk2[2 * sb + 1][0], srcB);
        unsigned a3 = (unsigned)__shfl((int)pk2[2 * sb][1], srcB);
        unsigned b3 = (unsigned)__shfl((int)pk2[2 * sb + 1][1], srcB);
        U8 pa;
        pa.u[0] = hi ? b0 : a0;
        pa.u[1] = hi ? b1 : a1;
        pa.u[2] = hi ? b2 : a2;
        pa.u[3] = hi ? b3 : a3;
        #pragma unroll
        for (int db = 0; db < 8; ++db) {
          int byte = (db * 16 + c) * VP + (sb * 32 + g * 8) * 2;
          U8 vb;
          vb.u[0] = *(const unsigned*)(VT + byte);
          vb.u[1] = *(const unsigned*)(VT + byte + 4);
          vb.u[2] = *(const unsigned*)(VT + byte + 8);
          vb.u[3] = *(const unsigned*)(VT + byte + 12);
          acc[db] = __builtin_amdgcn_mfma_f32_16x16x32_bf16(pa.v, vb.v, acc[db], 0, 0, 0);
        }
      }
    }

    if (!pf) break;
    conv();  // waits vmcnt for kreg/vreg (latency already hidden), VALU outside barrier
    __syncthreads();
    wr();    // only DS writes sit between the barriers
    __syncthreads();
  }

  // ---- epilogue: normalize, scatter ctx, write denom ----
  float inv = 1.0f / l_run;
  #pragma unroll
  for (int r = 0; r < 4; ++r) {
    float fi = __shfl(inv, g * 4 + r);
    int q2 = qbase + g * 4 + r;
    float* orow = Og + (size_t)(q2 * DEG + hm4) * TOKS + bhoff;
    #pragma unroll
    for (int db = 0; db < 8; ++db) orow[db * 16 + c] = acc[db][r] * fi;
  }
  // denom must use the TRUE row max (defer-max may leave m_run stale)
  if (g == 0)
    Dg[(size_t)(qbase + c) * (NB * NH) + b * NH + h] =
        l_run * __expf(m_run - m_true);
}

extern "C" void kernel_launch(void* const* d_in, const int* in_sizes, int n_in,
                              void* d_out, int out_size, void* d_ws, size_t ws_size,
                              hipStream_t stream) {
  (void)in_sizes; (void)n_in; (void)out_size; (void)d_ws; (void)ws_size;
  const float* q = (const float*)d_in[0];
  const float* k = (const float*)d_in[1];
  const float* v = (const float*)d_in[2];
  float* out = (float*)d_out;
  float* den = out + (size_t)S_TOK * NB * NH * DH;
  mlsa_fused<<<dim3(NQT * NB * NH), dim3(256), 0, stream>>>(q, k, v, out, den);
}